// Round 6
// baseline (393.333 us; speedup 1.0000x reference)
//
#include <hip/hip_runtime.h>
#include <hip/hip_bf16.h>

// Problem constants
#define B_SZ   4096
#define IN_SZ  4096
#define EPS_F  1e-5f
// SCALE = sqrt(256) = 16;  exp(s/16) = exp2(s * log2(e)/16)
#define CEXP   0.09016844005555896f

typedef __bf16 bf16x8 __attribute__((ext_vector_type(8)));
typedef float  f32x4  __attribute__((ext_vector_type(4)));
typedef float  f32x16 __attribute__((ext_vector_type(16)));

#if __has_builtin(__builtin_amdgcn_exp2f)
#define FAST_EXP2(x) __builtin_amdgcn_exp2f(x)
#else
#define FAST_EXP2(x) exp2f(x)
#endif

static __device__ __forceinline__ unsigned short f2bf(float f) {
    union { float f; unsigned int u; } c; c.f = f;
    unsigned int u = c.u;
    return (unsigned short)((u + 0x7FFFu + ((u >> 16) & 1u)) >> 16);
}
static __device__ __forceinline__ unsigned short bfbits(float f) {
    __bf16 h = (__bf16)f;
    return __builtin_bit_cast(unsigned short, h);
}
static __device__ __forceinline__ unsigned int pk2(float a, float b) {
    return (unsigned int)bfbits(a) | ((unsigned int)bfbits(b) << 16);
}

// ---------------- Kernel 1: per-column sum / sumsq ----------------
__global__ __launch_bounds__(256) void stats_kernel(const float* __restrict__ x,
                                                    float* __restrict__ colsum,
                                                    float* __restrict__ colsq) {
    int c4 = blockIdx.x * 256 + threadIdx.x;          // float4 column index 0..1023
    int r0 = blockIdx.y * 64;
    float4 s = {0.f, 0.f, 0.f, 0.f}, q = {0.f, 0.f, 0.f, 0.f};
    const float4* p = reinterpret_cast<const float4*>(x) + (size_t)r0 * 1024 + c4;
    #pragma unroll 4
    for (int r = 0; r < 64; ++r) {
        float4 v = p[(size_t)r * 1024];
        s.x += v.x; s.y += v.y; s.z += v.z; s.w += v.w;
        q.x += v.x * v.x; q.y += v.y * v.y; q.z += v.z * v.z; q.w += v.w * v.w;
    }
    int j = c4 * 4;
    atomicAdd(&colsum[j + 0], s.x); atomicAdd(&colsum[j + 1], s.y);
    atomicAdd(&colsum[j + 2], s.z); atomicAdd(&colsum[j + 3], s.w);
    atomicAdd(&colsq[j + 0], q.x);  atomicAdd(&colsq[j + 1], q.y);
    atomicAdd(&colsq[j + 2], q.z);  atomicAdd(&colsq[j + 3], q.w);
}

// ---------------- Kernel 2: BN fold + weight bf16 conversion ----------------
__global__ __launch_bounds__(256) void prep_kernel(const float* __restrict__ gamma,
                                                   const float* __restrict__ beta,
                                                   const float* __restrict__ WQ,
                                                   const float* __restrict__ WK,
                                                   const float* __restrict__ WV,
                                                   const float* __restrict__ colsum,
                                                   const float* __restrict__ colsq,
                                                   float* __restrict__ scale,
                                                   float* __restrict__ shift,
                                                   unsigned short* __restrict__ wbf) {
    int i = blockIdx.x * 256 + threadIdx.x;           // 0..65535
    if (i < IN_SZ) {
        float mean = colsum[i] * (1.0f / B_SZ);
        float var  = colsq[i] * (1.0f / B_SZ) - mean * mean;
        float sc   = gamma[i] * rsqrtf(var + EPS_F);
        scale[i] = sc;
        shift[i] = beta[i] - mean * sc;
    }
    wbf[i]           = f2bf(WQ[i]);
    wbf[65536 + i]   = f2bf(WK[i]);
    wbf[131072 + i]  = f2bf(WV[i]);
}

// ---------------- Kernel 3: fully-fused QKV + attention + residual ----------------
// One block = one batch; 4 waves; ONE barrier. 40960 B LDS -> 4 blocks/CU.
// A-fragments (normalized x) live in 32 VGPRs per lane (wave-invariant), no xr staging.
// All LDS tiles are unpadded + XOR-swizzled (write and read use the same involution):
//   qT  [256][16] bf16 @ 0      rows 32B,  swz: byte ^= ((byte>>7)&1)<<4
//   kT  [256][16] bf16 @ 8192   rows 32B,  same swz
//   vS  [16][256] bf16 @ 16384  rows 512B, swz: byte ^= ((byte>>9)&7)<<4
//   att 4 x [32][64] bf16 @ 24576 (per wave) rows 128B, swz: byte ^= ((byte>>7)&7)<<4
__global__ __launch_bounds__(256, 4) void attn4_kernel(
    const float* __restrict__ x,
    const float* __restrict__ scale,
    const float* __restrict__ shift,
    const unsigned short* __restrict__ wbf,
    const float* __restrict__ bQ,
    const float* __restrict__ bK,
    const float* __restrict__ bV,
    float* __restrict__ out)
{
    __shared__ __align__(16) unsigned short smem[20480];   // 40960 B
    char* const base = reinterpret_cast<char*>(smem);

    const int tid  = threadIdx.x;
    const int lane = tid & 63;
    const int w    = tid >> 6;                  // wave id 0..3
    const int b    = blockIdx.x;
    const int r16  = lane & 15;
    const int g4   = lane >> 4;                 // k-group 0..3

    char* const qT  = base;
    char* const kT  = base + 8192;
    char* const vS  = base + 16384;
    char* const att = base + 24576 + w * 4096;  // [32][64] bf16 per wave

    const float* xb = x + (size_t)b * IN_SZ;

    // ---- Phase A: A-fragments in registers: x_hat[p=r16][8g4+32kt .. +7] ----
    bf16x8 areg[8];
    {
        const float* xr  = xb    + r16 * 256;
        const float* scr = scale + r16 * 256;
        const float* shr = shift + r16 * 256;
        #pragma unroll
        for (int kt = 0; kt < 8; ++kt) {
            int c = 8 * g4 + 32 * kt;
            float4 x0 = *reinterpret_cast<const float4*>(xr + c);
            float4 x1 = *reinterpret_cast<const float4*>(xr + c + 4);
            float4 s0 = *reinterpret_cast<const float4*>(scr + c);
            float4 s1 = *reinterpret_cast<const float4*>(scr + c + 4);
            float4 h0 = *reinterpret_cast<const float4*>(shr + c);
            float4 h1 = *reinterpret_cast<const float4*>(shr + c + 4);
            union { bf16x8 v; unsigned int u[4]; } t;
            t.u[0] = pk2(fmaf(x0.x, s0.x, h0.x), fmaf(x0.y, s0.y, h0.y));
            t.u[1] = pk2(fmaf(x0.z, s0.z, h0.z), fmaf(x0.w, s0.w, h0.w));
            t.u[2] = pk2(fmaf(x1.x, s1.x, h1.x), fmaf(x1.y, s1.y, h1.y));
            t.u[3] = pk2(fmaf(x1.z, s1.z, h1.z), fmaf(x1.w, s1.w, h1.w));
            areg[kt] = t.v;
        }
    }

    // ---- Phase 1: QKV projections via mfma 16x16x32 ----
    // D[m=p][n=e-tile16]; A from areg; B[k=f][n=e] = W[e][f] from L2-hot global.
    for (int t = w; t < 48; t += 4) {
        int proj = t >> 4;                      // 0:Q 1:K 2:V
        int et   = t & 15;
        const unsigned short* Wg = wbf + proj * 65536 + (et * 16 + r16) * 256 + 8 * g4;
        f32x4 acc = {0.f, 0.f, 0.f, 0.f};
        #pragma unroll
        for (int kt = 0; kt < 8; ++kt) {
            bf16x8 bv = *reinterpret_cast<const bf16x8*>(Wg + 32 * kt);
            acc = __builtin_amdgcn_mfma_f32_16x16x32_bf16(areg[kt], bv, acc, 0, 0, 0);
        }
        const float* bias = (proj == 0) ? bQ : (proj == 1) ? bK : bV;
        float bvv = bias[et * 16 + r16];        // e = et*16 + r16 = D col
        // D layout (verified): col = lane&15 (=e), row = 4*(lane>>4)+reg (=p)
        if (proj < 2) {
            int e = et * 16 + r16;
            unsigned off = (unsigned)(e * 32 + 8 * g4);
            off ^= ((off >> 7) & 1u) << 4;
            *reinterpret_cast<uint2*>((proj == 0 ? qT : kT) + off) =
                make_uint2(pk2(acc[0] + bvv, acc[1] + bvv), pk2(acc[2] + bvv, acc[3] + bvv));
        } else {
            #pragma unroll
            for (int i = 0; i < 4; ++i) {
                int p = 4 * g4 + i;
                unsigned off = (unsigned)(p * 512 + (et * 16 + r16) * 2);
                off ^= ((off >> 9) & 7u) << 4;
                *reinterpret_cast<unsigned short*>(vS + off) = bfbits(acc[i] + bvv);
            }
        }
    }
    __syncthreads();

    // ---- Phase 2: streamed scores -> exp -> PV, deferred normalization ----
    const int c32  = lane & 31;
    const int hi32 = lane >> 5;
    float* ob = out + (size_t)b * IN_SZ;

    for (int et2 = w; et2 < 8; et2 += 4) {
        int e0 = et2 * 32;
        unsigned qoff = (unsigned)((e0 + c32) * 32 + 16 * hi32);
        qoff ^= ((qoff >> 7) & 1u) << 4;
        bf16x8 qfrag = *reinterpret_cast<const bf16x8*>(qT + qoff);
        f32x4 o0 = {0.f, 0.f, 0.f, 0.f}, o1 = {0.f, 0.f, 0.f, 0.f};
        float sum = 0.f;

        #pragma unroll
        for (int fb = 0; fb < 4; ++fb) {
            // scores^T tile (64 f-rows x 32 e-cols): s = K_tile * Q_tile^T (K=16=P)
            #pragma unroll
            for (int dd = 0; dd < 2; ++dd) {
                int d = 2 * fb + dd;
                unsigned koff = (unsigned)((32 * d + c32) * 32 + 16 * hi32);
                koff ^= ((koff >> 7) & 1u) << 4;
                bf16x8 kfrag = *reinterpret_cast<const bf16x8*>(kT + koff);
                f32x16 s;
                #pragma unroll
                for (int r = 0; r < 16; ++r) s[r] = 0.f;
                s = __builtin_amdgcn_mfma_f32_32x32x16_bf16(kfrag, qfrag, s, 0, 0, 0);
                // exp (no max subtraction: |s|*CEXP < ~1.2, safe), unnormalized P to LDS
                #pragma unroll
                for (int q = 0; q < 4; ++q) {
                    float p0 = FAST_EXP2(s[4*q+0] * CEXP);
                    float p1 = FAST_EXP2(s[4*q+1] * CEXP);
                    float p2 = FAST_EXP2(s[4*q+2] * CEXP);
                    float p3 = FAST_EXP2(s[4*q+3] * CEXP);
                    sum += (p0 + p1) + (p2 + p3);
                    unsigned aoff = (unsigned)(c32 * 128 + dd * 64 + 16 * q + 8 * hi32);
                    aoff ^= ((aoff >> 7) & 7u) << 4;
                    *reinterpret_cast<uint2*>(att + aoff) = make_uint2(pk2(p0, p1), pk2(p2, p3));
                }
            }
            // PV: A = P_u chunk (att, same-wave LDS), B = V rows (vS)
            #pragma unroll
            for (int kt2 = 0; kt2 < 2; ++kt2) {
                unsigned voff = (unsigned)(r16 * 512 + fb * 128 + kt2 * 64 + g4 * 16);
                voff ^= ((voff >> 9) & 7u) << 4;
                bf16x8 vfr = *reinterpret_cast<const bf16x8*>(vS + voff);
                unsigned a0off = (unsigned)(r16 * 128 + kt2 * 64 + g4 * 16);
                a0off ^= ((a0off >> 7) & 7u) << 4;
                bf16x8 a0 = *reinterpret_cast<const bf16x8*>(att + a0off);
                o0 = __builtin_amdgcn_mfma_f32_16x16x32_bf16(a0, vfr, o0, 0, 0, 0);
                unsigned a1off = (unsigned)((16 + r16) * 128 + kt2 * 64 + g4 * 16);
                a1off ^= ((a1off >> 7) & 7u) << 4;
                bf16x8 a1 = *reinterpret_cast<const bf16x8*>(att + a1off);
                o1 = __builtin_amdgcn_mfma_f32_16x16x32_bf16(a1, vfr, o1, 0, 0, 0);
            }
        }

        sum += __shfl_xor(sum, 32, 64);         // lane's sum covers e-col = e0 + (lane&31)
        float rinv = 1.0f / sum;
        // epilogue: out[b][e*16+p] = prod*rinv + x ; D: col=lane&15 (=p), row=4*g4+reg (=e off)
        #pragma unroll
        for (int r = 0; r < 4; ++r) {
            float ri0 = __shfl(rinv, 4 * g4 + r, 64);        // rinv of e-col 4*g4+r
            float ri1 = __shfl(rinv, 16 + 4 * g4 + r, 64);   // rinv of e-col 16+4*g4+r
            int j0 = (e0 + 4 * g4 + r) * 16 + r16;
            int j1 = (e0 + 16 + 4 * g4 + r) * 16 + r16;
            ob[j0] = o0[r] * ri0 + xb[j0];
            ob[j1] = o1[r] * ri1 + xb[j1];
        }
    }
}

extern "C" void kernel_launch(void* const* d_in, const int* in_sizes, int n_in,
                              void* d_out, int out_size, void* d_ws, size_t ws_size,
                              hipStream_t stream) {
    (void)in_sizes; (void)n_in; (void)out_size; (void)ws_size;
    const float* x     = (const float*)d_in[0];
    const float* gamma = (const float*)d_in[1];
    const float* beta  = (const float*)d_in[2];
    const float* WQ    = (const float*)d_in[3];
    const float* bQv   = (const float*)d_in[4];
    const float* WK    = (const float*)d_in[5];
    const float* bKv   = (const float*)d_in[6];
    const float* WV    = (const float*)d_in[7];
    const float* bVv   = (const float*)d_in[8];
    float* out = (float*)d_out;

    float* colsum = (float*)d_ws;                            // 4096 f32
    float* colsq  = colsum + 4096;
    float* scale  = colsum + 8192;
    float* shift  = colsum + 12288;
    unsigned short* wbf = (unsigned short*)(colsum + 16384); // 3 x 65536 bf16, ends @458752 B

    hipMemsetAsync(colsum, 0, 8192 * sizeof(float), stream);
    stats_kernel<<<dim3(4, 64), 256, 0, stream>>>(x, colsum, colsq);
    prep_kernel<<<256, 256, 0, stream>>>(gamma, beta, WQ, WK, WV, colsum, colsq, scale, shift, wbf);
    attn4_kernel<<<4096, 256, 0, stream>>>(x, scale, shift, wbf, bQv, bKv, bVv, out);
}